// Round 18
// baseline (36.987 us; speedup 1.0000x reference)
//
#include <hip/hip_runtime.h>

// Problem constants (fixed by the reference): C_IN=8, C_OUT=32, N_RINGS=2,
// WIDTH=4.0, sigma=4.0, rings={0,4}. n and B derived at runtime.
// batch is SORTED -> each graph's points are a contiguous index range.
//
// Hard-won config notes (do not regress):
//  * >~50 live floats/thread spills to scratch (rounds 0/5/6/7). acc[16]
//    + bas[8] + temps ≈ 35 live here is OK. Literal indexing only.
//  * DO NOT fuse per-channel stats atomics into graph_kernel (R5-R8 all
//    75-85us; removing them (R9) = 31us).
//  * DO NOT use threadfence/spin-counter epilogue fusion (R16: +18.5us).
//  * DO NOT have every block redundantly reduce out_raw for stats (R11: +13us).
//  * In-kernel 64-ary boundary search is fine (R10 vs R11).
//  * No hipMemsetAsync for small buffers (~40us as fillBufferAligned).
//  * R14 diagnostic: T_graph(warm)=18us of R12's 30. R17 (b64/acc[16] graph
//    + split epilogue) = 28.6. R18: x bypasses LDS (direct coalesced global
//    b64 gather: wave covers contiguous 512B per j-step); LDS holds bas only
//    (stride 9, odd -> 2-way max); invalid points masked by zeroed bas.
//    LDS 22.4KB -> ~11KB: blocks/CU 7 -> 8 (wave cap).

// 4-stage recursive-halving reduce-scatter over the 16 sub-lanes (lane bits
// 0..3). Literal constants only. After all stages acc[0] = sum over the
// 16-lane group of original component rev4(sub).
#define RS16_STAGE(M, HALF)                                 \
  {                                                         \
    const bool hi_ = (lane & (M)) != 0;                     \
    _Pragma("unroll")                                       \
    for (int k = 0; k < (HALF); ++k) {                      \
      float send = hi_ ? acc[k] : acc[(HALF) + k];          \
      float keep = hi_ ? acc[(HALF) + k] : acc[k];          \
      acc[k] = keep + __shfl_xor(send, (M), 64);            \
    }                                                       \
  }

#define NBLK_STATS 64

__device__ __forceinline__ int rev4(int s) {   // 4-bit bit-reversal
  return ((s & 1) << 3) | ((s & 2) << 1) | ((s & 4) >> 1) | ((s & 8) >> 3);
}

__device__ __forceinline__ void basis8(float rx, float ry, float rz,
                                       float* bas) {
  float d2 = rx * rx + ry * ry + rz * rz;
  float d = sqrtf(d2);
  // rings = {0, 4}, sigma = 4
  float r0 = __expf(-0.03125f * d2);          // exp(-0.5*(d/4)^2)
  float tt = (d - 4.0f) * 0.25f;
  float r1 = __expf(-0.5f * tt * tt);
  float idm = 1.0f / fmaxf(d, 1e-6f);
  float ax = rx * idm, ay = ry * idm, az = rz * idm;
  bas[0] = r0; bas[1] = r0 * ax; bas[2] = r0 * ay; bas[3] = r0 * az;
  bas[4] = r1; bas[5] = r1 * ax; bas[6] = r1 * ay; bas[7] = r1 * az;
}

// Wave-parallel 64-ary lower_bound: smallest i with a[i] >= key (a sorted).
__device__ __forceinline__ int lower_bound64(const int* __restrict__ a,
                                             int n, int key, int lane) {
  int lo = 0, len = n;
  while (len > 64) {
    int chunk = (len + 63) >> 6;               // ceil(len/64)
    int p = lo + lane * chunk;
    bool c = (p < lo + len) && (a[p] < key);   // p < lo+len <= n
    unsigned long long mask = __ballot(c);
    int m = __popcll(mask);                    // prefix count (a sorted)
    if (m == 0) { len = 0; break; }            // answer == lo
    int nlo = lo + (m - 1) * chunk + 1;        // a[nlo-1] < key
    int nhi = min(lo + m * chunk, lo + len);   // answer <= nhi
    lo = nlo;
    len = nhi - nlo;                           // <= chunk-1: strictly shrinks
  }
  if (len > 0) {
    int p = lo + lane;
    bool c = (lane < len) && (a[p] < key);
    lo += __popcll(__ballot(c));
  }
  return lo;
}

// ---------- kernel 1: one 256-thread block per graph ------------------------
// Search -> mean -> 64-point wave tiles. Lane computes its point's bas[8]
// (zeroed if invalid) -> LDS. Lane (q2=lane>>4, sub=lane&15) then gathers
// x channel-pairs DIRECTLY from global (coalesced 512B/wave per j) and
// accumulates acc[c*8+b] with 2 LDS b128 bas reads + 16 FMA per j.
__global__ __launch_bounds__(256) void graph_kernel(
    const float* __restrict__ x, const float* __restrict__ coords,
    const int* __restrict__ batch, const float* __restrict__ W,
    float* __restrict__ out_raw, int n) {
  __shared__ __align__(16) float pvb[4][64][9];  // bas[8] + pad (stride 9)
  __shared__ float sredm[4][3];   // per-wave coord sums
  __shared__ float sred[4][64];   // per-wave V partials
  __shared__ float sVg[64];       // aggregated V
  __shared__ float pre2[4][32];   // GEMM partials
  __shared__ float smean[3];
  __shared__ int sbound[2];

  const int g = blockIdx.x;
  const int t = threadIdx.x;
  const int lane = t & 63;
  const int wv = t >> 6;

  // ---- phase 0: graph boundaries (waves 0 and 1 in parallel) ----
  if (wv < 2) {
    int r = lower_bound64(batch, n, g + wv, lane);
    if (lane == 0) sbound[wv] = r;
  }
  __syncthreads();
  const int lo = sbound[0], hi = sbound[1];
  const int cnt = hi - lo;

  // ---- pass 1: mean of coords ----
  float s1 = 0.f, s2 = 0.f, s3 = 0.f;
  for (int i = lo + t; i < hi; i += 256) {
    s1 += coords[(size_t)i * 3 + 0];
    s2 += coords[(size_t)i * 3 + 1];
    s3 += coords[(size_t)i * 3 + 2];
  }
#pragma unroll
  for (int m = 1; m < 64; m <<= 1) {
    s1 += __shfl_xor(s1, m, 64);
    s2 += __shfl_xor(s2, m, 64);
    s3 += __shfl_xor(s3, m, 64);
  }
  if (lane == 0) { sredm[wv][0] = s1; sredm[wv][1] = s2; sredm[wv][2] = s3; }
  __syncthreads();
  if (t < 3) {
    smean[t] = (sredm[0][t] + sredm[1][t] + sredm[2][t] + sredm[3][t]) /
               (float)max(cnt, 1);
  }
  __syncthreads();
  const float mx = smean[0], my = smean[1], mz = smean[2];

  // ---- pass 2: tiles of 64 points per wave ----
  const int q2 = lane >> 4;       // channel-pair this lane accumulates
  const int sub = lane & 15;      // point sub-slot this lane reads
  float acc[16];
#pragma unroll
  for (int b = 0; b < 16; ++b) acc[b] = 0.f;

  const int niter = (cnt + 255) >> 8;
  for (int it = 0; it < niter; ++it) {
    const int pbase = lo + it * 256 + wv * 64;       // wave's tile start
    const int ip = pbase + lane;                     // point this lane writes
    const bool vp = ip < hi;
    const int ic = min(ip, n - 1);
    float cx = coords[(size_t)ic * 3 + 0];
    float cy = coords[(size_t)ic * 3 + 1];
    float cz = coords[(size_t)ic * 3 + 2];
    float bas[8];
    basis8(mx - cx, my - cy, mz - cz, bas);
    if (!vp) {
#pragma unroll
      for (int b = 0; b < 8; ++b) bas[b] = 0.f;      // masks clamped x gather
    }
    float* dst = &pvb[wv][lane][0];
    ((float4*)dst)[0] = make_float4(bas[0], bas[1], bas[2], bas[3]);
    ((float4*)dst)[1] = make_float4(bas[4], bas[5], bas[6], bas[7]);
    // same-wave LDS RAW: compiler inserts lgkmcnt wait; wave is lockstep.
#pragma unroll
    for (int j = 0; j < 4; ++j) {
      const int ipt = min(pbase + 16 * j + sub, n - 1);  // clamp; bas==0 masks
      float2 xp = ((const float2*)x)[(size_t)ipt * 4 + q2];  // coalesced 512B
      const float* src = &pvb[wv][16 * j + sub][0];
      float4 b03 = *(const float4*)(src);
      float4 b47 = *(const float4*)(src + 4);
      acc[0]  += xp.x * b03.x;  acc[1]  += xp.x * b03.y;
      acc[2]  += xp.x * b03.z;  acc[3]  += xp.x * b03.w;
      acc[4]  += xp.x * b47.x;  acc[5]  += xp.x * b47.y;
      acc[6]  += xp.x * b47.z;  acc[7]  += xp.x * b47.w;
      acc[8]  += xp.y * b03.x;  acc[9]  += xp.y * b03.y;
      acc[10] += xp.y * b03.z;  acc[11] += xp.y * b03.w;
      acc[12] += xp.y * b47.x;  acc[13] += xp.y * b47.y;
      acc[14] += xp.y * b47.z;  acc[15] += xp.y * b47.w;
    }
  }

  // ---- reduce acc[16] across the 16 sub-lanes (same q2) ----
  RS16_STAGE(1, 8)
  RS16_STAGE(2, 4)
  RS16_STAGE(4, 2)
  RS16_STAGE(8, 1)
  sred[wv][16 * q2 + rev4(sub)] = acc[0];
  __syncthreads();
  if (t < 64) sVg[t] = sred[0][t] + sred[1][t] + sred[2][t] + sred[3][t];
  __syncthreads();

  // ---- per-graph GEMM: out[o] = sum_k Vg[k] * W[o*64+k] ----
  const int o = t & 31;
  const int part = t >> 5;              // 0..7, k-chunks of 8
  const float* wrow = W + (size_t)o * 64 + part * 8;
  float4 w0 = *(const float4*)(wrow);
  float4 w1 = *(const float4*)(wrow + 4);
  float4 v0 = *(const float4*)(&sVg[part * 8]);
  float4 v1 = *(const float4*)(&sVg[part * 8 + 4]);
  float r = w0.x * v0.x + w0.y * v0.y + w0.z * v0.z + w0.w * v0.w +
            w1.x * v1.x + w1.y * v1.y + w1.z * v1.z + w1.w * v1.w;
  r += __shfl_xor(r, 32, 64);           // combine part pairs within wave
  if (lane < 32) pre2[wv][o] = r;
  __syncthreads();
  if (t < 32) {
    out_raw[(size_t)g * 32 + t] =
        pre2[0][t] + pre2[1][t] + pre2[2][t] + pre2[3][t];
  }
}

// ---------- kernel 2: per-channel partial sum/sumsq over out_raw ------------
// NBLK_STATS blocks; block b writes its partial {sum[32]|sumsq[32]} to
// spart[b*64 .. b*64+63]. Plain stores — no atomics, no pre-zeroing.
__global__ __launch_bounds__(256) void stats_kernel(
    const float* __restrict__ out_raw, float* __restrict__ spart, int B) {
  __shared__ float red[4][32], redq[4][32];
  const int t = threadIdx.x;
  const int o = t & 31;
  const int lane = t & 63;
  const int wv = t >> 6;
  const int stride = NBLK_STATS * 256;  // multiple of 32 -> o constant/thread
  float s = 0.f, q = 0.f;
  for (int e = blockIdx.x * 256 + t; e < B * 32; e += stride) {
    float val = out_raw[e];
    s += val;
    q += val * val;
  }
  s += __shfl_xor(s, 32, 64);
  q += __shfl_xor(q, 32, 64);
  if (lane < 32) { red[wv][o] = s; redq[wv][o] = q; }
  __syncthreads();
  if (t < 32) {
    spart[blockIdx.x * 64 + t] =
        red[0][t] + red[1][t] + red[2][t] + red[3][t];
    spart[blockIdx.x * 64 + 32 + t] =
        redq[0][t] + redq[1][t] + redq[2][t] + redq[3][t];
  }
}

// ---------- kernel 3: fold partials + batchnorm + relu(|.|-bias) ------------
__global__ __launch_bounds__(256) void final_kernel(
    const float* __restrict__ out_raw, const float* __restrict__ spart,
    const float* __restrict__ gamma, const float* __restrict__ beta,
    const float* __restrict__ act_bias, float* __restrict__ out, int B) {
  __shared__ float ssums[64];
  __shared__ float sscale[32], sshift[32], sbias[32];
  const int t = threadIdx.x;
  const int total = B * 32;

  if (t < 64) {
    float s = 0.f;
#pragma unroll 8
    for (int b = 0; b < NBLK_STATS; ++b) s += spart[b * 64 + t];
    ssums[t] = s;
  }
  __syncthreads();
  if (t < 32) {
    float invB = 1.0f / (float)B;
    float mu = ssums[t] * invB;
    float var = ssums[32 + t] * invB - mu * mu;
    float sc = rsqrtf(var + 1e-5f) * gamma[t];
    sscale[t] = sc;
    sshift[t] = beta[t] - mu * sc;
    sbias[t]  = act_bias[t];
  }
  __syncthreads();

  // write this block's slice: 4 consecutive outputs per thread (float4)
  const int base = (blockIdx.x * 256 + t) * 4;
  if (base < total) {
    float4 vv = *(const float4*)(out_raw + base);
    const int o0 = base & 31;             // multiple of 4
    float r0 = fabsf(vv.x * sscale[o0 + 0] + sshift[o0 + 0]) - sbias[o0 + 0];
    float r1 = fabsf(vv.y * sscale[o0 + 1] + sshift[o0 + 1]) - sbias[o0 + 1];
    float r2 = fabsf(vv.z * sscale[o0 + 2] + sshift[o0 + 2]) - sbias[o0 + 2];
    float r3 = fabsf(vv.w * sscale[o0 + 3] + sshift[o0 + 3]) - sbias[o0 + 3];
    *(float4*)(out + base) = make_float4(fmaxf(r0, 0.f), fmaxf(r1, 0.f),
                                         fmaxf(r2, 0.f), fmaxf(r3, 0.f));
  }
}

extern "C" void kernel_launch(void* const* d_in, const int* in_sizes, int n_in,
                              void* d_out, int out_size, void* d_ws, size_t ws_size,
                              hipStream_t stream) {
  const float* x      = (const float*)d_in[0];
  const float* coords = (const float*)d_in[1];
  const int*   batch  = (const int*)d_in[2];
  const float* W      = (const float*)d_in[3];
  const float* gamma  = (const float*)d_in[4];
  const float* beta   = (const float*)d_in[5];
  const float* abias  = (const float*)d_in[6];
  float* out = (float*)d_out;

  int n = in_sizes[2];          // N points
  int B = out_size / 32;        // graphs

  // ws layout: out_raw[B*32] | spart[NBLK_STATS*64]
  float* out_raw = (float*)d_ws;
  float* spart   = out_raw + (size_t)B * 32;

  graph_kernel<<<B, 256, 0, stream>>>(x, coords, batch, W, out_raw, n);
  stats_kernel<<<NBLK_STATS, 256, 0, stream>>>(out_raw, spart, B);
  int nblk_final = (B * 32 + 1023) / 1024;
  final_kernel<<<nblk_final, 256, 0, stream>>>(out_raw, spart, gamma, beta, abias, out, B);
}

// Round 19
// 26.648 us; speedup vs baseline: 1.3880x; 1.3880x over previous
//
#include <hip/hip_runtime.h>

// Problem constants (fixed by the reference): C_IN=8, C_OUT=32, N_RINGS=2,
// WIDTH=4.0, sigma=4.0, rings={0,4}. n and B derived at runtime.
// batch is SORTED -> each graph's points are a contiguous index range.
//
// Hard-won config notes (do not regress):
//  * >~50 live floats/thread spills to scratch (rounds 0/5/6/7). acc[16]
//    + bas[8] + temps ≈ 46 live is OK. Literal indexing only.
//  * DO NOT fuse per-channel stats atomics into graph_kernel (R5-R8 all
//    75-85us; removing them (R9) = 31us).
//  * DO NOT use threadfence/spin-counter epilogue fusion (R16: +18.5us).
//  * DO NOT have every block redundantly reduce out_raw for stats (R11: +13us).
//  * DO NOT move the x-gather from LDS staging to per-j global loads in the
//    inner loop (R18: +8.4us — global latency lands on the FMA chain even
//    when perfectly coalesced). x goes global->reg->LDS->reg once per tile.
//  * In-kernel 64-ary boundary search is fine (R10 vs R11).
//  * No hipMemsetAsync for small buffers (~40us as fillBufferAligned).
//  * R14 diagnostic: T_graph(warm)≈16.5-18us; epilogue+gaps≈12us. R17
//    (b64/acc[16] graph + split epilogue) = 28.6us = best. R19 = exact R17
//    + distributed spart fold in final_kernel (256 threads x 16 loads vs
//    64 threads x 64 loads).

// 4-stage recursive-halving reduce-scatter over the 16 sub-lanes (lane bits
// 0..3). Literal constants only. After all stages acc[0] = sum over the
// 16-lane group of original component rev4(sub).
#define RS16_STAGE(M, HALF)                                 \
  {                                                         \
    const bool hi_ = (lane & (M)) != 0;                     \
    _Pragma("unroll")                                       \
    for (int k = 0; k < (HALF); ++k) {                      \
      float send = hi_ ? acc[k] : acc[(HALF) + k];          \
      float keep = hi_ ? acc[(HALF) + k] : acc[k];          \
      acc[k] = keep + __shfl_xor(send, (M), 64);            \
    }                                                       \
  }

#define NBLK_STATS 64

__device__ __forceinline__ int rev4(int s) {   // 4-bit bit-reversal
  return ((s & 1) << 3) | ((s & 2) << 1) | ((s & 4) >> 1) | ((s & 8) >> 3);
}

__device__ __forceinline__ void basis8(float rx, float ry, float rz,
                                       float* bas) {
  float d2 = rx * rx + ry * ry + rz * rz;
  float d = sqrtf(d2);
  // rings = {0, 4}, sigma = 4
  float r0 = __expf(-0.03125f * d2);          // exp(-0.5*(d/4)^2)
  float tt = (d - 4.0f) * 0.25f;
  float r1 = __expf(-0.5f * tt * tt);
  float idm = 1.0f / fmaxf(d, 1e-6f);
  float ax = rx * idm, ay = ry * idm, az = rz * idm;
  bas[0] = r0; bas[1] = r0 * ax; bas[2] = r0 * ay; bas[3] = r0 * az;
  bas[4] = r1; bas[5] = r1 * ax; bas[6] = r1 * ay; bas[7] = r1 * az;
}

// Wave-parallel 64-ary lower_bound: smallest i with a[i] >= key (a sorted).
__device__ __forceinline__ int lower_bound64(const int* __restrict__ a,
                                             int n, int key, int lane) {
  int lo = 0, len = n;
  while (len > 64) {
    int chunk = (len + 63) >> 6;               // ceil(len/64)
    int p = lo + lane * chunk;
    bool c = (p < lo + len) && (a[p] < key);   // p < lo+len <= n
    unsigned long long mask = __ballot(c);
    int m = __popcll(mask);                    // prefix count (a sorted)
    if (m == 0) { len = 0; break; }            // answer == lo
    int nlo = lo + (m - 1) * chunk + 1;        // a[nlo-1] < key
    int nhi = min(lo + m * chunk, lo + len);   // answer <= nhi
    lo = nlo;
    len = nhi - nlo;                           // <= chunk-1: strictly shrinks
  }
  if (len > 0) {
    int p = lo + lane;
    bool c = (lane < len) && (a[p] < key);
    lo += __popcll(__ballot(c));
  }
  return lo;
}

// ---------- kernel 1: one 256-thread block per graph (EXACT R17) ------------
// Search -> mean -> 64-point wave tiles. Lane (q2=lane>>4, sub=lane&15)
// accumulates acc[c*8+b] for channels {2q2, 2q2+1} over points p=16j+sub:
// per j ONE ds_read_b64 (xv pair) + 2 ds_read_b128 (bas) + 16 FMA.
__global__ __launch_bounds__(256) void graph_kernel(
    const float* __restrict__ x, const float* __restrict__ coords,
    const int* __restrict__ batch, const float* __restrict__ W,
    float* __restrict__ out_raw, int n) {
  __shared__ __align__(16) float pv[4][64][20];  // xv[8]|bas[8]|pad[4]
  __shared__ float sredm[4][3];   // per-wave coord sums
  __shared__ float sred[4][64];   // per-wave V partials
  __shared__ float sVg[64];       // aggregated V
  __shared__ float pre2[4][32];   // GEMM partials
  __shared__ float smean[3];
  __shared__ int sbound[2];

  const int g = blockIdx.x;
  const int t = threadIdx.x;
  const int lane = t & 63;
  const int wv = t >> 6;

  // ---- phase 0: graph boundaries (waves 0 and 1 in parallel) ----
  if (wv < 2) {
    int r = lower_bound64(batch, n, g + wv, lane);
    if (lane == 0) sbound[wv] = r;
  }
  __syncthreads();
  const int lo = sbound[0], hi = sbound[1];
  const int cnt = hi - lo;

  // ---- pass 1: mean of coords ----
  float s1 = 0.f, s2 = 0.f, s3 = 0.f;
  for (int i = lo + t; i < hi; i += 256) {
    s1 += coords[(size_t)i * 3 + 0];
    s2 += coords[(size_t)i * 3 + 1];
    s3 += coords[(size_t)i * 3 + 2];
  }
#pragma unroll
  for (int m = 1; m < 64; m <<= 1) {
    s1 += __shfl_xor(s1, m, 64);
    s2 += __shfl_xor(s2, m, 64);
    s3 += __shfl_xor(s3, m, 64);
  }
  if (lane == 0) { sredm[wv][0] = s1; sredm[wv][1] = s2; sredm[wv][2] = s3; }
  __syncthreads();
  if (t < 3) {
    smean[t] = (sredm[0][t] + sredm[1][t] + sredm[2][t] + sredm[3][t]) /
               (float)max(cnt, 1);
  }
  __syncthreads();
  const float mx = smean[0], my = smean[1], mz = smean[2];

  // ---- pass 2: tiles of 64 points per wave ----
  const int q2 = lane >> 4;       // channel-pair this lane accumulates
  const int sub = lane & 15;      // point sub-slot this lane reads
  float acc[16];
#pragma unroll
  for (int b = 0; b < 16; ++b) acc[b] = 0.f;

  const int niter = (cnt + 255) >> 8;
  for (int it = 0; it < niter; ++it) {
    const int ip = lo + it * 256 + wv * 64 + lane;   // point this lane writes
    const bool vp = ip < hi;
    const int ic = min(ip, n - 1);
    float cx = coords[(size_t)ic * 3 + 0];
    float cy = coords[(size_t)ic * 3 + 1];
    float cz = coords[(size_t)ic * 3 + 2];
    float bas[8];
    basis8(mx - cx, my - cy, mz - cz, bas);
    float4 xa = ((const float4*)x)[2 * (size_t)ic];
    float4 xb = ((const float4*)x)[2 * (size_t)ic + 1];
    if (!vp) {
      xa = make_float4(0.f, 0.f, 0.f, 0.f);
      xb = make_float4(0.f, 0.f, 0.f, 0.f);
    }
    float* dst = &pv[wv][lane][0];
    ((float4*)dst)[0] = xa;                               // xv[0..3]
    ((float4*)dst)[1] = xb;                               // xv[4..7]
    ((float4*)dst)[2] = make_float4(bas[0], bas[1], bas[2], bas[3]);
    ((float4*)dst)[3] = make_float4(bas[4], bas[5], bas[6], bas[7]);
    // same-wave LDS RAW: compiler inserts lgkmcnt wait; wave is lockstep.
#pragma unroll
    for (int j = 0; j < 4; ++j) {
      const float* src = &pv[wv][16 * j + sub][0];
      float2 xp = *(const float2*)(src + 2 * q2);         // ds_read_b64
      float4 b03 = *(const float4*)(src + 8);
      float4 b47 = *(const float4*)(src + 12);
      acc[0]  += xp.x * b03.x;  acc[1]  += xp.x * b03.y;
      acc[2]  += xp.x * b03.z;  acc[3]  += xp.x * b03.w;
      acc[4]  += xp.x * b47.x;  acc[5]  += xp.x * b47.y;
      acc[6]  += xp.x * b47.z;  acc[7]  += xp.x * b47.w;
      acc[8]  += xp.y * b03.x;  acc[9]  += xp.y * b03.y;
      acc[10] += xp.y * b03.z;  acc[11] += xp.y * b03.w;
      acc[12] += xp.y * b47.x;  acc[13] += xp.y * b47.y;
      acc[14] += xp.y * b47.z;  acc[15] += xp.y * b47.w;
    }
  }

  // ---- reduce acc[16] across the 16 sub-lanes (same q2) ----
  RS16_STAGE(1, 8)
  RS16_STAGE(2, 4)
  RS16_STAGE(4, 2)
  RS16_STAGE(8, 1)
  sred[wv][16 * q2 + rev4(sub)] = acc[0];
  __syncthreads();
  if (t < 64) sVg[t] = sred[0][t] + sred[1][t] + sred[2][t] + sred[3][t];
  __syncthreads();

  // ---- per-graph GEMM: out[o] = sum_k Vg[k] * W[o*64+k] ----
  const int o = t & 31;
  const int part = t >> 5;              // 0..7, k-chunks of 8
  const float* wrow = W + (size_t)o * 64 + part * 8;
  float4 w0 = *(const float4*)(wrow);
  float4 w1 = *(const float4*)(wrow + 4);
  float4 v0 = *(const float4*)(&sVg[part * 8]);
  float4 v1 = *(const float4*)(&sVg[part * 8 + 4]);
  float r = w0.x * v0.x + w0.y * v0.y + w0.z * v0.z + w0.w * v0.w +
            w1.x * v1.x + w1.y * v1.y + w1.z * v1.z + w1.w * v1.w;
  r += __shfl_xor(r, 32, 64);           // combine part pairs within wave
  if (lane < 32) pre2[wv][o] = r;
  __syncthreads();
  if (t < 32) {
    out_raw[(size_t)g * 32 + t] =
        pre2[0][t] + pre2[1][t] + pre2[2][t] + pre2[3][t];
  }
}

// ---------- kernel 2: per-channel partial sum/sumsq over out_raw ------------
// NBLK_STATS blocks; block b writes its partial {sum[32]|sumsq[32]} to
// spart[b*64 .. b*64+63]. Plain stores — no atomics, no pre-zeroing.
__global__ __launch_bounds__(256) void stats_kernel(
    const float* __restrict__ out_raw, float* __restrict__ spart, int B) {
  __shared__ float red[4][32], redq[4][32];
  const int t = threadIdx.x;
  const int o = t & 31;
  const int lane = t & 63;
  const int wv = t >> 6;
  const int stride = NBLK_STATS * 256;  // multiple of 32 -> o constant/thread
  float s = 0.f, q = 0.f;
  for (int e = blockIdx.x * 256 + t; e < B * 32; e += stride) {
    float val = out_raw[e];
    s += val;
    q += val * val;
  }
  s += __shfl_xor(s, 32, 64);
  q += __shfl_xor(q, 32, 64);
  if (lane < 32) { red[wv][o] = s; redq[wv][o] = q; }
  __syncthreads();
  if (t < 32) {
    spart[blockIdx.x * 64 + t] =
        red[0][t] + red[1][t] + red[2][t] + red[3][t];
    spart[blockIdx.x * 64 + 32 + t] =
        redq[0][t] + redq[1][t] + redq[2][t] + redq[3][t];
  }
}

// ---------- kernel 3: fold partials + batchnorm + relu(|.|-bias) ------------
// Distributed fold: thread t loads 16 spart values for channel-slot t&63
// (4 threads per slot, 16 blocks each), LDS-combined. 4x shorter dependent-
// load chain than the old 64-loads-on-64-threads fold.
__global__ __launch_bounds__(256) void final_kernel(
    const float* __restrict__ out_raw, const float* __restrict__ spart,
    const float* __restrict__ gamma, const float* __restrict__ beta,
    const float* __restrict__ act_bias, float* __restrict__ out, int B) {
  __shared__ float sfold[4][64];
  __shared__ float sscale[32], sshift[32], sbias[32];
  const int t = threadIdx.x;
  const int total = B * 32;

  {
    const int slot = t & 63;            // channel-slot (0..63)
    const int grp = t >> 6;             // which 16-block group (0..3)
    float s = 0.f;
#pragma unroll
    for (int b = 0; b < 16; ++b)
      s += spart[(grp * 16 + b) * 64 + slot];
    sfold[grp][slot] = s;
  }
  __syncthreads();
  if (t < 32) {
    float ssum = sfold[0][t] + sfold[1][t] + sfold[2][t] + sfold[3][t];
    float ssq  = sfold[0][32 + t] + sfold[1][32 + t] +
                 sfold[2][32 + t] + sfold[3][32 + t];
    float invB = 1.0f / (float)B;
    float mu = ssum * invB;
    float var = ssq * invB - mu * mu;
    float sc = rsqrtf(var + 1e-5f) * gamma[t];
    sscale[t] = sc;
    sshift[t] = beta[t] - mu * sc;
    sbias[t]  = act_bias[t];
  }
  __syncthreads();

  // write this block's slice: 4 consecutive outputs per thread (float4)
  const int base = (blockIdx.x * 256 + t) * 4;
  if (base < total) {
    float4 vv = *(const float4*)(out_raw + base);
    const int o0 = base & 31;             // multiple of 4
    float r0 = fabsf(vv.x * sscale[o0 + 0] + sshift[o0 + 0]) - sbias[o0 + 0];
    float r1 = fabsf(vv.y * sscale[o0 + 1] + sshift[o0 + 1]) - sbias[o0 + 1];
    float r2 = fabsf(vv.z * sscale[o0 + 2] + sshift[o0 + 2]) - sbias[o0 + 2];
    float r3 = fabsf(vv.w * sscale[o0 + 3] + sshift[o0 + 3]) - sbias[o0 + 3];
    *(float4*)(out + base) = make_float4(fmaxf(r0, 0.f), fmaxf(r1, 0.f),
                                         fmaxf(r2, 0.f), fmaxf(r3, 0.f));
  }
}

extern "C" void kernel_launch(void* const* d_in, const int* in_sizes, int n_in,
                              void* d_out, int out_size, void* d_ws, size_t ws_size,
                              hipStream_t stream) {
  const float* x      = (const float*)d_in[0];
  const float* coords = (const float*)d_in[1];
  const int*   batch  = (const int*)d_in[2];
  const float* W      = (const float*)d_in[3];
  const float* gamma  = (const float*)d_in[4];
  const float* beta   = (const float*)d_in[5];
  const float* abias  = (const float*)d_in[6];
  float* out = (float*)d_out;

  int n = in_sizes[2];          // N points
  int B = out_size / 32;        // graphs

  // ws layout: out_raw[B*32] | spart[NBLK_STATS*64]
  float* out_raw = (float*)d_ws;
  float* spart   = out_raw + (size_t)B * 32;

  graph_kernel<<<B, 256, 0, stream>>>(x, coords, batch, W, out_raw, n);
  stats_kernel<<<NBLK_STATS, 256, 0, stream>>>(out_raw, spart, B);
  int nblk_final = (B * 32 + 1023) / 1024;
  final_kernel<<<nblk_final, 256, 0, stream>>>(out_raw, spart, gamma, beta, abias, out, B);
}

// Round 20
// 24.959 us; speedup vs baseline: 1.4819x; 1.0677x over previous
//
#include <hip/hip_runtime.h>

// Problem constants (fixed by the reference): C_IN=8, C_OUT=32, N_RINGS=2,
// WIDTH=4.0, sigma=4.0, rings={0,4}. n and B derived at runtime.
// batch is SORTED -> each graph's points are a contiguous index range.
//
// Hard-won config notes (do not regress):
//  * >~50 live floats/thread spills to scratch (rounds 0/5/6/7). acc[16]
//    + strip caches ≈ 40 live peak here. Literal indexing only.
//  * DO NOT fuse per-channel stats atomics into graph_kernel (R5-R8 all
//    75-85us; removing them (R9) = 31us).
//  * DO NOT use threadfence/spin-counter epilogue fusion (R16: +18.5us).
//  * DO NOT have every block redundantly reduce out_raw for stats (R11: +13us).
//  * DO NOT move the x-gather to per-j global loads in the inner loop
//    (R18: +8.4us). x goes global->reg->LDS->reg once per tile.
//  * In-kernel 64-ary boundary search is fine (R10 vs R11).
//  * No hipMemsetAsync for small buffers (~40us as fillBufferAligned).
//  * R14 diagnostic: T_graph(warm)≈16.5-18us; epilogue+gaps≈10us.
//  * R19 = 26.6us best: b64/acc[16] graph + split stats + distributed-fold
//    final. R20 = R19 + strip-cache (coords+x for tiles 0/1 loaded during
//    pass 1; x latency hides under mean reduce; pass 2 global-load-free for
//    cnt<=512). R6's version of this was confounded by fused atomics+v[64].

// 4-stage recursive-halving reduce-scatter over the 16 sub-lanes (lane bits
// 0..3). Literal constants only. After all stages acc[0] = sum over the
// 16-lane group of original component rev4(sub).
#define RS16_STAGE(M, HALF)                                 \
  {                                                         \
    const bool hi_ = (lane & (M)) != 0;                     \
    _Pragma("unroll")                                       \
    for (int k = 0; k < (HALF); ++k) {                      \
      float send = hi_ ? acc[k] : acc[(HALF) + k];          \
      float keep = hi_ ? acc[(HALF) + k] : acc[k];          \
      acc[k] = keep + __shfl_xor(send, (M), 64);            \
    }                                                       \
  }

#define NBLK_STATS 64

__device__ __forceinline__ int rev4(int s) {   // 4-bit bit-reversal
  return ((s & 1) << 3) | ((s & 2) << 1) | ((s & 4) >> 1) | ((s & 8) >> 3);
}

__device__ __forceinline__ void basis8(float rx, float ry, float rz,
                                       float* bas) {
  float d2 = rx * rx + ry * ry + rz * rz;
  float d = sqrtf(d2);
  // rings = {0, 4}, sigma = 4
  float r0 = __expf(-0.03125f * d2);          // exp(-0.5*(d/4)^2)
  float tt = (d - 4.0f) * 0.25f;
  float r1 = __expf(-0.5f * tt * tt);
  float idm = 1.0f / fmaxf(d, 1e-6f);
  float ax = rx * idm, ay = ry * idm, az = rz * idm;
  bas[0] = r0; bas[1] = r0 * ax; bas[2] = r0 * ay; bas[3] = r0 * az;
  bas[4] = r1; bas[5] = r1 * ax; bas[6] = r1 * ay; bas[7] = r1 * az;
}

// Wave-parallel 64-ary lower_bound: smallest i with a[i] >= key (a sorted).
__device__ __forceinline__ int lower_bound64(const int* __restrict__ a,
                                             int n, int key, int lane) {
  int lo = 0, len = n;
  while (len > 64) {
    int chunk = (len + 63) >> 6;               // ceil(len/64)
    int p = lo + lane * chunk;
    bool c = (p < lo + len) && (a[p] < key);   // p < lo+len <= n
    unsigned long long mask = __ballot(c);
    int m = __popcll(mask);                    // prefix count (a sorted)
    if (m == 0) { len = 0; break; }            // answer == lo
    int nlo = lo + (m - 1) * chunk + 1;        // a[nlo-1] < key
    int nhi = min(lo + m * chunk, lo + len);   // answer <= nhi
    lo = nlo;
    len = nhi - nlo;                           // <= chunk-1: strictly shrinks
  }
  if (len > 0) {
    int p = lo + lane;
    bool c = (lane < len) && (a[p] < key);
    lo += __popcll(__ballot(c));
  }
  return lo;
}

// ---------- kernel 1: one 256-thread block per graph ------------------------
// Search -> strip loads (coords+x for tiles 0/1, latency hides under mean)
// -> mean from cached coords -> wave tiles with zero global loads for
// cnt<=512 (tail tiles >=2 reload). Inner loop: per j ONE ds_read_b64 (xv
// pair) + 2 ds_read_b128 (bas) + 16 FMA into acc[16].
__global__ __launch_bounds__(256) void graph_kernel(
    const float* __restrict__ x, const float* __restrict__ coords,
    const int* __restrict__ batch, const float* __restrict__ W,
    float* __restrict__ out_raw, int n) {
  __shared__ __align__(16) float pv[4][64][20];  // xv[8]|bas[8]|pad[4]
  __shared__ float sredm[4][3];   // per-wave coord sums
  __shared__ float sred[4][64];   // per-wave V partials
  __shared__ float sVg[64];       // aggregated V
  __shared__ float pre2[4][32];   // GEMM partials
  __shared__ float smean[3];
  __shared__ int sbound[2];

  const int g = blockIdx.x;
  const int t = threadIdx.x;
  const int lane = t & 63;
  const int wv = t >> 6;

  // ---- phase 0: graph boundaries (waves 0 and 1 in parallel) ----
  if (wv < 2) {
    int r = lower_bound64(batch, n, g + wv, lane);
    if (lane == 0) sbound[wv] = r;
  }
  __syncthreads();
  const int lo = sbound[0], hi = sbound[1];
  const int cnt = hi - lo;

  // ---- strip loads: tiles 0/1 coords + x, issued before the mean pass ----
  // Tile it covers point lo + it*256 + t, so strip A = tile 0, B = tile 1.
  const bool vA = t < cnt;
  const bool vB = 256 + t < cnt;
  const int iA = min(lo + t, n - 1);
  const int iB = min(lo + 256 + t, n - 1);
  float cAx = coords[(size_t)iA * 3 + 0];
  float cAy = coords[(size_t)iA * 3 + 1];
  float cAz = coords[(size_t)iA * 3 + 2];
  float cBx = coords[(size_t)iB * 3 + 0];
  float cBy = coords[(size_t)iB * 3 + 1];
  float cBz = coords[(size_t)iB * 3 + 2];
  float4 xA0 = ((const float4*)x)[2 * (size_t)iA];
  float4 xA1 = ((const float4*)x)[2 * (size_t)iA + 1];
  float4 xB0 = ((const float4*)x)[2 * (size_t)iB];
  float4 xB1 = ((const float4*)x)[2 * (size_t)iB + 1];

  // ---- pass 1: mean of coords (cached strips + rare tail) ----
  float s1 = (vA ? cAx : 0.f) + (vB ? cBx : 0.f);
  float s2 = (vA ? cAy : 0.f) + (vB ? cBy : 0.f);
  float s3 = (vA ? cAz : 0.f) + (vB ? cBz : 0.f);
  for (int i = lo + 512 + t; i < hi; i += 256) {   // ~14% of graphs
    s1 += coords[(size_t)i * 3 + 0];
    s2 += coords[(size_t)i * 3 + 1];
    s3 += coords[(size_t)i * 3 + 2];
  }
#pragma unroll
  for (int m = 1; m < 64; m <<= 1) {
    s1 += __shfl_xor(s1, m, 64);
    s2 += __shfl_xor(s2, m, 64);
    s3 += __shfl_xor(s3, m, 64);
  }
  if (lane == 0) { sredm[wv][0] = s1; sredm[wv][1] = s2; sredm[wv][2] = s3; }
  __syncthreads();
  if (t < 3) {
    smean[t] = (sredm[0][t] + sredm[1][t] + sredm[2][t] + sredm[3][t]) /
               (float)max(cnt, 1);
  }
  __syncthreads();
  const float mx = smean[0], my = smean[1], mz = smean[2];

  // ---- pass 2: tiles of 64 points per wave ----
  const int q2 = lane >> 4;       // channel-pair this lane accumulates
  const int sub = lane & 15;      // point sub-slot this lane reads
  float acc[16];
#pragma unroll
  for (int b = 0; b < 16; ++b) acc[b] = 0.f;

  // tile 0 (always; empty graphs produce zeros via masked x)
  {
    float bas[8];
    basis8(mx - cAx, my - cAy, mz - cAz, bas);
    if (!vA) {
      xA0 = make_float4(0.f, 0.f, 0.f, 0.f);
      xA1 = make_float4(0.f, 0.f, 0.f, 0.f);
    }
    float* dst = &pv[wv][lane][0];
    ((float4*)dst)[0] = xA0;
    ((float4*)dst)[1] = xA1;
    ((float4*)dst)[2] = make_float4(bas[0], bas[1], bas[2], bas[3]);
    ((float4*)dst)[3] = make_float4(bas[4], bas[5], bas[6], bas[7]);
#pragma unroll
    for (int j = 0; j < 4; ++j) {
      const float* src = &pv[wv][16 * j + sub][0];
      float2 xp = *(const float2*)(src + 2 * q2);
      float4 b03 = *(const float4*)(src + 8);
      float4 b47 = *(const float4*)(src + 12);
      acc[0]  += xp.x * b03.x;  acc[1]  += xp.x * b03.y;
      acc[2]  += xp.x * b03.z;  acc[3]  += xp.x * b03.w;
      acc[4]  += xp.x * b47.x;  acc[5]  += xp.x * b47.y;
      acc[6]  += xp.x * b47.z;  acc[7]  += xp.x * b47.w;
      acc[8]  += xp.y * b03.x;  acc[9]  += xp.y * b03.y;
      acc[10] += xp.y * b03.z;  acc[11] += xp.y * b03.w;
      acc[12] += xp.y * b47.x;  acc[13] += xp.y * b47.y;
      acc[14] += xp.y * b47.z;  acc[15] += xp.y * b47.w;
    }
  }
  // tile 1 (block-uniform branch)
  if (cnt > 256) {
    float bas[8];
    basis8(mx - cBx, my - cBy, mz - cBz, bas);
    if (!vB) {
      xB0 = make_float4(0.f, 0.f, 0.f, 0.f);
      xB1 = make_float4(0.f, 0.f, 0.f, 0.f);
    }
    float* dst = &pv[wv][lane][0];
    ((float4*)dst)[0] = xB0;
    ((float4*)dst)[1] = xB1;
    ((float4*)dst)[2] = make_float4(bas[0], bas[1], bas[2], bas[3]);
    ((float4*)dst)[3] = make_float4(bas[4], bas[5], bas[6], bas[7]);
#pragma unroll
    for (int j = 0; j < 4; ++j) {
      const float* src = &pv[wv][16 * j + sub][0];
      float2 xp = *(const float2*)(src + 2 * q2);
      float4 b03 = *(const float4*)(src + 8);
      float4 b47 = *(const float4*)(src + 12);
      acc[0]  += xp.x * b03.x;  acc[1]  += xp.x * b03.y;
      acc[2]  += xp.x * b03.z;  acc[3]  += xp.x * b03.w;
      acc[4]  += xp.x * b47.x;  acc[5]  += xp.x * b47.y;
      acc[6]  += xp.x * b47.z;  acc[7]  += xp.x * b47.w;
      acc[8]  += xp.y * b03.x;  acc[9]  += xp.y * b03.y;
      acc[10] += xp.y * b03.z;  acc[11] += xp.y * b03.w;
      acc[12] += xp.y * b47.x;  acc[13] += xp.y * b47.y;
      acc[14] += xp.y * b47.z;  acc[15] += xp.y * b47.w;
    }
  }
  // tail tiles (cnt > 512, ~14% of graphs): reload from global
  const int niter = (cnt + 255) >> 8;
  for (int it = 2; it < niter; ++it) {
    const int ip = lo + it * 256 + wv * 64 + lane;
    const bool vp = ip < hi;
    const int ic = min(ip, n - 1);
    float cx = coords[(size_t)ic * 3 + 0];
    float cy = coords[(size_t)ic * 3 + 1];
    float cz = coords[(size_t)ic * 3 + 2];
    float bas[8];
    basis8(mx - cx, my - cy, mz - cz, bas);
    float4 xa = ((const float4*)x)[2 * (size_t)ic];
    float4 xb = ((const float4*)x)[2 * (size_t)ic + 1];
    if (!vp) {
      xa = make_float4(0.f, 0.f, 0.f, 0.f);
      xb = make_float4(0.f, 0.f, 0.f, 0.f);
    }
    float* dst = &pv[wv][lane][0];
    ((float4*)dst)[0] = xa;
    ((float4*)dst)[1] = xb;
    ((float4*)dst)[2] = make_float4(bas[0], bas[1], bas[2], bas[3]);
    ((float4*)dst)[3] = make_float4(bas[4], bas[5], bas[6], bas[7]);
#pragma unroll
    for (int j = 0; j < 4; ++j) {
      const float* src = &pv[wv][16 * j + sub][0];
      float2 xp = *(const float2*)(src + 2 * q2);
      float4 b03 = *(const float4*)(src + 8);
      float4 b47 = *(const float4*)(src + 12);
      acc[0]  += xp.x * b03.x;  acc[1]  += xp.x * b03.y;
      acc[2]  += xp.x * b03.z;  acc[3]  += xp.x * b03.w;
      acc[4]  += xp.x * b47.x;  acc[5]  += xp.x * b47.y;
      acc[6]  += xp.x * b47.z;  acc[7]  += xp.x * b47.w;
      acc[8]  += xp.y * b03.x;  acc[9]  += xp.y * b03.y;
      acc[10] += xp.y * b03.z;  acc[11] += xp.y * b03.w;
      acc[12] += xp.y * b47.x;  acc[13] += xp.y * b47.y;
      acc[14] += xp.y * b47.z;  acc[15] += xp.y * b47.w;
    }
  }

  // ---- reduce acc[16] across the 16 sub-lanes (same q2) ----
  RS16_STAGE(1, 8)
  RS16_STAGE(2, 4)
  RS16_STAGE(4, 2)
  RS16_STAGE(8, 1)
  sred[wv][16 * q2 + rev4(sub)] = acc[0];
  __syncthreads();
  if (t < 64) sVg[t] = sred[0][t] + sred[1][t] + sred[2][t] + sred[3][t];
  __syncthreads();

  // ---- per-graph GEMM: out[o] = sum_k Vg[k] * W[o*64+k] ----
  const int o = t & 31;
  const int part = t >> 5;              // 0..7, k-chunks of 8
  const float* wrow = W + (size_t)o * 64 + part * 8;
  float4 w0 = *(const float4*)(wrow);
  float4 w1 = *(const float4*)(wrow + 4);
  float4 v0 = *(const float4*)(&sVg[part * 8]);
  float4 v1 = *(const float4*)(&sVg[part * 8 + 4]);
  float r = w0.x * v0.x + w0.y * v0.y + w0.z * v0.z + w0.w * v0.w +
            w1.x * v1.x + w1.y * v1.y + w1.z * v1.z + w1.w * v1.w;
  r += __shfl_xor(r, 32, 64);           // combine part pairs within wave
  if (lane < 32) pre2[wv][o] = r;
  __syncthreads();
  if (t < 32) {
    out_raw[(size_t)g * 32 + t] =
        pre2[0][t] + pre2[1][t] + pre2[2][t] + pre2[3][t];
  }
}

// ---------- kernel 2: per-channel partial sum/sumsq over out_raw ------------
// NBLK_STATS blocks; block b writes its partial {sum[32]|sumsq[32]} to
// spart[b*64 .. b*64+63]. Plain stores — no atomics, no pre-zeroing.
__global__ __launch_bounds__(256) void stats_kernel(
    const float* __restrict__ out_raw, float* __restrict__ spart, int B) {
  __shared__ float red[4][32], redq[4][32];
  const int t = threadIdx.x;
  const int o = t & 31;
  const int lane = t & 63;
  const int wv = t >> 6;
  const int stride = NBLK_STATS * 256;  // multiple of 32 -> o constant/thread
  float s = 0.f, q = 0.f;
  for (int e = blockIdx.x * 256 + t; e < B * 32; e += stride) {
    float val = out_raw[e];
    s += val;
    q += val * val;
  }
  s += __shfl_xor(s, 32, 64);
  q += __shfl_xor(q, 32, 64);
  if (lane < 32) { red[wv][o] = s; redq[wv][o] = q; }
  __syncthreads();
  if (t < 32) {
    spart[blockIdx.x * 64 + t] =
        red[0][t] + red[1][t] + red[2][t] + red[3][t];
    spart[blockIdx.x * 64 + 32 + t] =
        redq[0][t] + redq[1][t] + redq[2][t] + redq[3][t];
  }
}

// ---------- kernel 3: fold partials + batchnorm + relu(|.|-bias) ------------
// Distributed fold: thread t loads 16 spart values for channel-slot t&63
// (4 threads per slot, 16 blocks each), LDS-combined.
__global__ __launch_bounds__(256) void final_kernel(
    const float* __restrict__ out_raw, const float* __restrict__ spart,
    const float* __restrict__ gamma, const float* __restrict__ beta,
    const float* __restrict__ act_bias, float* __restrict__ out, int B) {
  __shared__ float sfold[4][64];
  __shared__ float sscale[32], sshift[32], sbias[32];
  const int t = threadIdx.x;
  const int total = B * 32;

  {
    const int slot = t & 63;            // channel-slot (0..63)
    const int grp = t >> 6;             // which 16-block group (0..3)
    float s = 0.f;
#pragma unroll
    for (int b = 0; b < 16; ++b)
      s += spart[(grp * 16 + b) * 64 + slot];
    sfold[grp][slot] = s;
  }
  __syncthreads();
  if (t < 32) {
    float ssum = sfold[0][t] + sfold[1][t] + sfold[2][t] + sfold[3][t];
    float ssq  = sfold[0][32 + t] + sfold[1][32 + t] +
                 sfold[2][32 + t] + sfold[3][32 + t];
    float invB = 1.0f / (float)B;
    float mu = ssum * invB;
    float var = ssq * invB - mu * mu;
    float sc = rsqrtf(var + 1e-5f) * gamma[t];
    sscale[t] = sc;
    sshift[t] = beta[t] - mu * sc;
    sbias[t]  = act_bias[t];
  }
  __syncthreads();

  // write this block's slice: 4 consecutive outputs per thread (float4)
  const int base = (blockIdx.x * 256 + t) * 4;
  if (base < total) {
    float4 vv = *(const float4*)(out_raw + base);
    const int o0 = base & 31;             // multiple of 4
    float r0 = fabsf(vv.x * sscale[o0 + 0] + sshift[o0 + 0]) - sbias[o0 + 0];
    float r1 = fabsf(vv.y * sscale[o0 + 1] + sshift[o0 + 1]) - sbias[o0 + 1];
    float r2 = fabsf(vv.z * sscale[o0 + 2] + sshift[o0 + 2]) - sbias[o0 + 2];
    float r3 = fabsf(vv.w * sscale[o0 + 3] + sshift[o0 + 3]) - sbias[o0 + 3];
    *(float4*)(out + base) = make_float4(fmaxf(r0, 0.f), fmaxf(r1, 0.f),
                                         fmaxf(r2, 0.f), fmaxf(r3, 0.f));
  }
}

extern "C" void kernel_launch(void* const* d_in, const int* in_sizes, int n_in,
                              void* d_out, int out_size, void* d_ws, size_t ws_size,
                              hipStream_t stream) {
  const float* x      = (const float*)d_in[0];
  const float* coords = (const float*)d_in[1];
  const int*   batch  = (const int*)d_in[2];
  const float* W      = (const float*)d_in[3];
  const float* gamma  = (const float*)d_in[4];
  const float* beta   = (const float*)d_in[5];
  const float* abias  = (const float*)d_in[6];
  float* out = (float*)d_out;

  int n = in_sizes[2];          // N points
  int B = out_size / 32;        // graphs

  // ws layout: out_raw[B*32] | spart[NBLK_STATS*64]
  float* out_raw = (float*)d_ws;
  float* spart   = out_raw + (size_t)B * 32;

  graph_kernel<<<B, 256, 0, stream>>>(x, coords, batch, W, out_raw, n);
  stats_kernel<<<NBLK_STATS, 256, 0, stream>>>(out_raw, spart, B);
  int nblk_final = (B * 32 + 1023) / 1024;
  final_kernel<<<nblk_final, 256, 0, stream>>>(out_raw, spart, gamma, beta, abias, out, B);
}